// Round 11
// baseline (232.052 us; speedup 1.0000x reference)
//
#include <hip/hip_runtime.h>

// f16 vector types
typedef _Float16 h2 __attribute__((ext_vector_type(2)));
typedef __fp16   h2n __attribute__((ext_vector_type(2)));   // builtin native
typedef __fp16   h8n __attribute__((ext_vector_type(8)));   // MFMA operand
typedef float    f32x4 __attribute__((ext_vector_type(4))); // MFMA accum
struct alignas(16) H8 { h2 a, b, c, d; };          // 8 halves = one b128
struct alignas(8)  U2 { unsigned int x, y; };      // one b64

static __device__ __forceinline__ f32x4 mfma16(const H8& A, const H8& B, f32x4 C) {
    return __builtin_amdgcn_mfma_f32_16x16x32_f16(
        __builtin_bit_cast(h8n, A), __builtin_bit_cast(h8n, B), C, 0, 0, 0);
}

static __device__ __forceinline__ float dot2(h2 a, h2 b, float c) {
#if __has_builtin(__builtin_amdgcn_fdot2)
    return __builtin_amdgcn_fdot2(__builtin_bit_cast(h2n, a),
                                  __builtin_bit_cast(h2n, b), c, false);
#else
    return c + (float)a[0] * (float)b[0] + (float)a[1] * (float)b[1];
#endif
}
static __device__ __forceinline__ float dot4(const H8& x, const H8& w, float c) {
    return dot2(x.d, w.d, dot2(x.c, w.c, dot2(x.b, w.b, dot2(x.a, w.a, c))));
}
static __device__ __forceinline__ h2 pk(float a, float b) {
#if __has_builtin(__builtin_amdgcn_cvt_pkrtz)
    return __builtin_bit_cast(h2, __builtin_amdgcn_cvt_pkrtz(a, b));
#else
    h2 r; r[0] = (_Float16)a; r[1] = (_Float16)b; return r;
#endif
}
static __device__ __forceinline__ float fast_tanh(float v) {
    return 1.0f - 2.0f / (__expf(2.0f * v) + 1.0f);
}
static __device__ __forceinline__ void softmax10(float* row) {
    float mx = row[0];
#pragma unroll
    for (int i = 1; i < 10; ++i) mx = fmaxf(mx, row[i]);
    float e[10]; float sm = 0.0f;
#pragma unroll
    for (int i = 0; i < 10; ++i) { e[i] = __expf(row[i] - mx); sm += e[i]; }
    const float inv = 1.0f / sm;
#pragma unroll
    for (int i = 0; i < 10; ++i) row[i] = e[i] * inv;
}

// ---- f16 weight cache (device global, rewritten every launch — deterministic)
#define WST 0          // w_state [256][128]
#define WIN 32768      // w_info  [512][128]
#define WQS 98304      // wq_s    [128][64]
#define WKS 106496     // wk_s    [128][64]
#define WSA 114688     // w_sagg  [256][64]
#define WQD 131072     // wq_d    [128][512]
#define WKD 196608     // wk_d    [128][512]
#define WDA 262144     // w_dagg  [7][512]
#define WTOT 265728
__device__ __align__(16) unsigned short W16[WTOT];

// ---- x in f16, node-major [B][10][1024] (rewritten every launch).
// Sized for the fixed problem B=4096 (in_sizes[0]/10240).
#define XCAP 4096
__device__ __align__(16) unsigned short X16g[(long)XCAP * 10240];

__global__ __launch_bounds__(256) void cvt_w(
        const float* __restrict__ ws,  const float* __restrict__ wi,
        const float* __restrict__ wqs, const float* __restrict__ wks,
        const float* __restrict__ wsa, const float* __restrict__ wqd,
        const float* __restrict__ wkd, const float* __restrict__ wda) {
    const int i2 = (blockIdx.x * 256 + threadIdx.x) * 2;
    if (i2 >= WTOT) return;
    const float* src; int off;
    if      (i2 < WIN) { src = ws;  off = WST; }
    else if (i2 < WQS) { src = wi;  off = WIN; }
    else if (i2 < WKS) { src = wqs; off = WQS; }
    else if (i2 < WSA) { src = wks; off = WKS; }
    else if (i2 < WQD) { src = wsa; off = WSA; }
    else if (i2 < WKD) { src = wqd; off = WQD; }
    else if (i2 < WDA) { src = wkd; off = WKD; }
    else               { src = wda; off = WDA; }
    const float a = src[i2 - off], b2 = src[i2 - off + 1];
    *(unsigned int*)(W16 + i2) = __builtin_bit_cast(unsigned int, pk(a, b2));
}

// x [B][1024][10] f32 -> X16g [B][10][1024] f16. Fully coalesced both ways.
__global__ __launch_bounds__(256) void xcvt(const float* __restrict__ x, int B) {
    const long b = blockIdx.x;
    if (b >= B || b >= XCAP) return;
    const int t = threadIdx.x;
    const float* xg = x + b * 10240 + t * 40;
    float v[40];
#pragma unroll
    for (int k = 0; k < 10; ++k) {
        const float4 q = *(const float4*)(xg + (k << 2));
        v[k * 4 + 0] = q.x; v[k * 4 + 1] = q.y; v[k * 4 + 2] = q.z; v[k * 4 + 3] = q.w;
    }
    unsigned short* dst = X16g + b * 10240;
#pragma unroll
    for (int n = 0; n < 10; ++n) {
        U2 u;
        u.x = __builtin_bit_cast(unsigned int, pk(v[n], v[10 + n]));
        u.y = __builtin_bit_cast(unsigned int, pk(v[20 + n], v[30 + n]));
        *(U2*)(dst + n * 1024 + (t << 2)) = u;
    }
}

// ---------------- LDS layout (2 samples/block) ----------------
// Per sample: XB region 5632 shorts (state [10][260] -> qT 4x[10][136] ->
//             Y0/ys f32 [256][11]); SB region 5840 shorts (shot [10][584] ->
//             scene f32 [256][7]); SMf region 816 f32.
// Totals: XB 22528 B + SB 23360 B + SMf 6528 B = 52416 B -> 3 blocks/CU.
#define XSTR 5632
#define SSTR 5840
#define MSTR 816
#define SO(n,c)  ((n)*584  + (c))
#define STO(n,c) ((n)*260  + (c))

#define QST 0              // qsT [10][136] f16
#define KST 1360
#define QDT 2720
#define KDT 4080
// SMf per-sample layout
#define RED2 0             // tanh wave partials [4][17]
#define ASTA 68            // A_sta [10][10]
#define BSO  168           // Bs/As [10][10]
#define BDO  268           // Bd/Ad [10][10]
#define PRD  368           // w_dagg partials [280]
#define P0O  648           // P0 [7][10]
#define TTO  718           // T  [7][10]
#define MUO  788           // head partials [2 waves][14]

#define RSQRT128 0.08838834764831843f

__global__ __launch_bounds__(256, 3)
void hgcn_fused(const float* __restrict__ esp,
                const float* __restrict__ b_state,const float* __restrict__ b_info,
                const float* __restrict__ C_s,    const float* __restrict__ alpha_s,
                const float* __restrict__ b_sagg, const float* __restrict__ C_d,
                const float* __restrict__ alpha_d,const float* __restrict__ b_dagg,
                const float* __restrict__ S_d,    const float* __restrict__ alpha_dif,
                const float* __restrict__ w_mot,  const float* __restrict__ b_mot,
                const float* __restrict__ w_mean, const float* __restrict__ b_mean,
                const float* __restrict__ w_logv, const float* __restrict__ b_logv,
                float* __restrict__ out, int B)
{
    __shared__ __align__(16) unsigned short XB[2 * XSTR];
    __shared__ __align__(16) unsigned short SB[2 * SSTR];
    __shared__ __align__(16) float SMf[2 * MSTR];

    const int tl = threadIdx.x;
    const long b0 = (long)blockIdx.x * 2;
    const long b1 = (b0 + 1 < B) ? (b0 + 1) : b0;
    const int wv = tl >> 6, ln = tl & 63;
    const int ar = ln & 15;                 // MFMA A-row / D-col lane index
    const int bn = (ar < 10) ? ar : 9;      // clamped node for B-frags
    const int kq = ln >> 4;                 // k-octet selector (0..3)

    const float aS  = alpha_s[0];
    const float aD  = alpha_d[0];
    const float aDf = alpha_dif[0];

    // Zero A_sta early (read only after two barriers below).
    if (tl < 100) { SMf[ASTA + tl] = 0.0f; SMf[MSTR + ASTA + tl] = 0.0f; }

    // ---- P1 (MFMA, 2 samples): state + info gconvs, K=128/group.
    // B-frags: ONE contiguous b128 from X16g per (kt,sample). A-frags (W16)
    // loaded once, used for both samples.
    {
        const unsigned short* xg0 = X16g + b0 * 10240 + bn * 1024;
        const unsigned short* xg1 = X16g + b1 * 10240 + bn * 1024;
        const f32x4 z = {0.0f, 0.0f, 0.0f, 0.0f};
        f32x4 stk[2][2][2];
#pragma unroll
        for (int sp = 0; sp < 2; ++sp)
#pragma unroll
            for (int gi = 0; gi < 2; ++gi)
#pragma unroll
                for (int mt = 0; mt < 2; ++mt) stk[sp][gi][mt] = z;
#pragma unroll
        for (int gi = 0; gi < 2; ++gi) {
            const int grp = (wv << 1) + gi;
            const int cb = grp << 7;
            f32x4 inf[2][4];
#pragma unroll
            for (int sp = 0; sp < 2; ++sp)
#pragma unroll
                for (int mt = 0; mt < 4; ++mt) inf[sp][mt] = z;
#pragma unroll
            for (int kt = 0; kt < 4; ++kt) {
                const int ka = cb + (kt << 5) + (kq << 3);
                const H8 bf0 = *(const H8*)(xg0 + ka);
                const H8 bf1 = *(const H8*)(xg1 + ka);
                const int ko = (kt << 5) + (kq << 3);
                const unsigned short* wsrow = W16 + WST + (((grp << 5) + ar) << 7) + ko;
                const unsigned short* wirow = W16 + WIN + (((grp << 6) + ar) << 7) + ko;
                const H8 as0 = *(const H8*)(wsrow);
                const H8 as1 = *(const H8*)(wsrow + (16 << 7));
                const H8 ai0 = *(const H8*)(wirow);
                const H8 ai1 = *(const H8*)(wirow + (16 << 7));
                const H8 ai2 = *(const H8*)(wirow + (32 << 7));
                const H8 ai3 = *(const H8*)(wirow + (48 << 7));
                stk[0][gi][0] = mfma16(as0, bf0, stk[0][gi][0]);
                stk[0][gi][1] = mfma16(as1, bf0, stk[0][gi][1]);
                stk[1][gi][0] = mfma16(as0, bf1, stk[1][gi][0]);
                stk[1][gi][1] = mfma16(as1, bf1, stk[1][gi][1]);
                inf[0][0] = mfma16(ai0, bf0, inf[0][0]);
                inf[0][1] = mfma16(ai1, bf0, inf[0][1]);
                inf[0][2] = mfma16(ai2, bf0, inf[0][2]);
                inf[0][3] = mfma16(ai3, bf0, inf[0][3]);
                inf[1][0] = mfma16(ai0, bf1, inf[1][0]);
                inf[1][1] = mfma16(ai1, bf1, inf[1][1]);
                inf[1][2] = mfma16(ai2, bf1, inf[1][2]);
                inf[1][3] = mfma16(ai3, bf1, inf[1][3]);
            }
            if (ar < 10) {
#pragma unroll
                for (int sp = 0; sp < 2; ++sp) {
                    unsigned short* SBs = SB + sp * SSTR;
#pragma unroll
                    for (int mt = 0; mt < 4; ++mt) {
                        U2 u;
                        u.x = __builtin_bit_cast(unsigned int, pk(inf[sp][mt][0], inf[sp][mt][1]));
                        u.y = __builtin_bit_cast(unsigned int, pk(inf[sp][mt][2], inf[sp][mt][3]));
                        *(U2*)(SBs + SO(ar, (grp << 6) + (mt << 4) + (kq << 2))) = u;
                    }
                }
            }
        }
        if (ar < 10) {
#pragma unroll
            for (int sp = 0; sp < 2; ++sp) {
                unsigned short* XBs = XB + sp * XSTR;
#pragma unroll
                for (int gi = 0; gi < 2; ++gi) {
#pragma unroll
                    for (int mt = 0; mt < 2; ++mt) {
                        U2 u;
                        u.x = __builtin_bit_cast(unsigned int, pk(stk[sp][gi][mt][0], stk[sp][gi][mt][1]));
                        u.y = __builtin_bit_cast(unsigned int, pk(stk[sp][gi][mt][2], stk[sp][gi][mt][3]));
                        *(U2*)(XBs + STO(ar, (((wv << 1) + gi) << 5) + (mt << 4) + (kq << 2))) = u;
                    }
                }
            }
        }
    }
    __syncthreads();

    // ---- P2: tanh diffs, per sample, shfl butterfly ----
    {
        const float bb = b_state[tl];
#pragma unroll
        for (int sp = 0; sp < 2; ++sp) {
            const unsigned short* XBs = XB + sp * XSTR;
            float* SMs = SMf + sp * MSTR;
            float st[10];
#pragma unroll
            for (int n = 0; n < 10; ++n) {
                const unsigned short u = XBs[STO(n, tl)];
                st[n] = fmaxf((float)__builtin_bit_cast(_Float16, u) + bb, 0.0f);
            }
            float red[17];
#pragma unroll
            for (int p = 0; p < 17; ++p) {
                const int n = (p < 9) ? p : (p - 9);
                const int m = (p < 9) ? (p + 1) : (p - 9 + 2);
                red[p] = fast_tanh(st[n] - st[m]);
            }
#pragma unroll
            for (int stp = 1; stp < 64; stp <<= 1)
#pragma unroll
                for (int p = 0; p < 17; ++p) red[p] += __shfl_xor(red[p], stp);
            if (ln == 0) {
#pragma unroll
                for (int p = 0; p < 17; ++p) SMs[RED2 + wv * 17 + p] = red[p];
            }
        }
    }
    __syncthreads();

    // ---- P2b: assemble A_sta (both samples); zeroing done at kernel start ----
    if (tl < 17) {
#pragma unroll
        for (int sp = 0; sp < 2; ++sp) {
            float* SMs = SMf + sp * MSTR;
            const float s = (SMs[RED2 + tl] + SMs[RED2 + 17 + tl] +
                             SMs[RED2 + 34 + tl] + SMs[RED2 + 51 + tl]) * (1.0f / 256.0f);
            const int n = (tl < 9) ? tl : (tl - 9);
            const int m = (tl < 9) ? (tl + 1) : (tl - 9 + 2);
            SMs[ASTA + n * 10 + m] = s;
            SMs[ASTA + m * 10 + n] = -s;
        }
    } else if (tl < 27) {
        const int n = tl - 17;
        SMf[ASTA + n * 10 + n] = 1.0f;
        SMf[MSTR + ASTA + n * 10 + n] = 1.0f;
    }
    __syncthreads();

    // ---- P3: shot = relu(S0 . A_sta + b_info), per sample ----
    {
        const int c0 = tl << 1;
        const float bi0 = b_info[c0], bi1 = b_info[c0 + 1];
#pragma unroll
        for (int sp = 0; sp < 2; ++sp) {
            unsigned short* SBs = SB + sp * SSTR;
            const float* SMs = SMf + sp * MSTR;
            float sa[10], sb2[10];
#pragma unroll
            for (int n = 0; n < 10; ++n) {
                const h2 v = __builtin_bit_cast(h2, *(const unsigned int*)(SBs + SO(n, c0)));
                sa[n] = (float)v[0]; sb2[n] = (float)v[1];
            }
            unsigned int o10[10];
#pragma unroll
            for (int m = 0; m < 10; ++m) {
                float t0 = bi0, t1 = bi1;
#pragma unroll
                for (int n = 0; n < 10; ++n) {
                    const float a = SMs[ASTA + n * 10 + m];
                    t0 += sa[n] * a; t1 += sb2[n] * a;
                }
                o10[m] = __builtin_bit_cast(unsigned int, pk(fmaxf(t0, 0.0f), fmaxf(t1, 0.0f)));
            }
#pragma unroll
            for (int m = 0; m < 10; ++m)
                *(unsigned int*)(SBs + SO(m, c0)) = o10[m];
        }
    }
    __syncthreads();

    // ---- P4 (MFMA, 2 samples): q_d/k_d (K=512) + q_s/k_s (grouped K=64) ----
    {
        const f32x4 z = {0.0f, 0.0f, 0.0f, 0.0f};
        f32x4 qa[2][2], ka4[2][2];
#pragma unroll
        for (int sp = 0; sp < 2; ++sp)
#pragma unroll
            for (int h = 0; h < 2; ++h) { qa[sp][h] = z; ka4[sp][h] = z; }
        const unsigned short* wq0 = W16 + WQD + (((wv << 5) + ar) << 9);
        const unsigned short* wk0 = W16 + WKD + (((wv << 5) + ar) << 9);
        for (int kt = 0; kt < 16; ++kt) {
            const int ko = (kt << 5) + (kq << 3);
            const H8 bf0 = *(const H8*)(SB + SO(bn, ko));
            const H8 bf1 = *(const H8*)(SB + SSTR + SO(bn, ko));
            const H8 aq0 = *(const H8*)(wq0 + ko);
            const H8 aq1 = *(const H8*)(wq0 + (16 << 9) + ko);
            const H8 ak0 = *(const H8*)(wk0 + ko);
            const H8 ak1 = *(const H8*)(wk0 + (16 << 9) + ko);
            qa[0][0] = mfma16(aq0, bf0, qa[0][0]);
            qa[0][1] = mfma16(aq1, bf0, qa[0][1]);
            ka4[0][0] = mfma16(ak0, bf0, ka4[0][0]);
            ka4[0][1] = mfma16(ak1, bf0, ka4[0][1]);
            qa[1][0] = mfma16(aq0, bf1, qa[1][0]);
            qa[1][1] = mfma16(aq1, bf1, qa[1][1]);
            ka4[1][0] = mfma16(ak0, bf1, ka4[1][0]);
            ka4[1][1] = mfma16(ak1, bf1, ka4[1][1]);
        }
        if (ar < 10) {
            const int oc = (wv << 5) + (kq << 2);
#pragma unroll
            for (int sp = 0; sp < 2; ++sp) {
                unsigned short* XBs = XB + sp * XSTR;
                U2 u;
                u.x = __builtin_bit_cast(unsigned int, pk(qa[sp][0][0], qa[sp][0][1]));
                u.y = __builtin_bit_cast(unsigned int, pk(qa[sp][0][2], qa[sp][0][3]));
                *(U2*)(XBs + QDT + ar * 136 + oc) = u;
                u.x = __builtin_bit_cast(unsigned int, pk(qa[sp][1][0], qa[sp][1][1]));
                u.y = __builtin_bit_cast(unsigned int, pk(qa[sp][1][2], qa[sp][1][3]));
                *(U2*)(XBs + QDT + ar * 136 + oc + 16) = u;
                u.x = __builtin_bit_cast(unsigned int, pk(ka4[sp][0][0], ka4[sp][0][1]));
                u.y = __builtin_bit_cast(unsigned int, pk(ka4[sp][0][2], ka4[sp][0][3]));
                *(U2*)(XBs + KDT + ar * 136 + oc) = u;
                u.x = __builtin_bit_cast(unsigned int, pk(ka4[sp][1][0], ka4[sp][1][1]));
                u.y = __builtin_bit_cast(unsigned int, pk(ka4[sp][1][2], ka4[sp][1][3]));
                *(U2*)(XBs + KDT + ar * 136 + oc + 16) = u;
            }
        }
#pragma unroll
        for (int gi = 0; gi < 2; ++gi) {
            const int gs = (wv << 1) + gi;
            f32x4 qs[2], ks[2];
            qs[0] = z; qs[1] = z; ks[0] = z; ks[1] = z;
#pragma unroll
            for (int kt = 0; kt < 2; ++kt) {
                const int ko = (kt << 5) + (kq << 3);
                const H8 aq = *(const H8*)(W16 + WQS + (((gs << 4) + ar) << 6) + ko);
                const H8 ak = *(const H8*)(W16 + WKS + (((gs << 4) + ar) << 6) + ko);
                const H8 bf0 = *(const H8*)(SB + SO(bn, (gs << 6) + ko));
                const H8 bf1 = *(const H8*)(SB + SSTR + SO(bn, (gs << 6) + ko));
                qs[0] = mfma16(aq, bf0, qs[0]);
                ks[0] = mfma16(ak, bf0, ks[0]);
                qs[1] = mfma16(aq, bf1, qs[1]);
                ks[1] = mfma16(ak, bf1, ks[1]);
            }
            if (ar < 10) {
                const int oc = (gs << 4) + (kq << 2);
#pragma unroll
                for (int sp = 0; sp < 2; ++sp) {
                    unsigned short* XBs = XB + sp * XSTR;
                    U2 u;
                    u.x = __builtin_bit_cast(unsigned int, pk(qs[sp][0], qs[sp][1]));
                    u.y = __builtin_bit_cast(unsigned int, pk(qs[sp][2], qs[sp][3]));
                    *(U2*)(XBs + QST + ar * 136 + oc) = u;
                    u.x = __builtin_bit_cast(unsigned int, pk(ks[sp][0], ks[sp][1]));
                    u.y = __builtin_bit_cast(unsigned int, pk(ks[sp][2], ks[sp][3]));
                    *(U2*)(XBs + KST + ar * 136 + oc) = u;
                }
            }
        }
    }
    __syncthreads();

    // ---- P5: Bs|Bd logits, both samples ----
    if (tl < 200) {
        const int t = (tl < 100) ? tl : (tl - 100);
        const int n = t / 10, m = t - (t / 10) * 10;
        const int d = (n > m) ? (n - m) : (m - n);
        const float band = (d <= 3) ? 1.0f : 0.0f;
        const float Cv = (tl < 100) ? C_s[n * 10 + m] : C_d[n * 10 + m];
        const float al = (tl < 100) ? aS : aD;
        const int qoff = ((tl < 100) ? QST : QDT) + n * 136;
        const int koff = ((tl < 100) ? KST : KDT) + m * 136;
        const int dsto = (tl < 100) ? (BSO + t) : (BDO + t);
#pragma unroll
        for (int sp = 0; sp < 2; ++sp) {
            const unsigned short* q = XB + sp * XSTR + qoff;
            const unsigned short* k = XB + sp * XSTR + koff;
            float s = 0.0f;
#pragma unroll
            for (int c8 = 0; c8 < 16; ++c8) {
                const H8 qv = *(const H8*)(q + (c8 << 3));
                const H8 kv = *(const H8*)(k + (c8 << 3));
                s = dot4(qv, kv, s);
            }
            SMf[sp * MSTR + dsto] = al * (s * RSQRT128) + Cv + band;
        }
    }
    __syncthreads();

    // ---- P6: Y0 + PRD partials + softmaxes, both samples ----
    {
        const int p = tl >> 1, kh = tl & 1;
        const int gs = p >> 4, ls = p & 15;
        const int o0 = (gs << 5) + ls, o1 = o0 + 16;
        const int cb = (gs << 6) + (kh << 5);
        const unsigned short* w0 = W16 + WSA + (o0 << 6) + (kh << 5);
        const unsigned short* w1 = W16 + WSA + (o1 << 6) + (kh << 5);
#pragma unroll
        for (int sp = 0; sp < 2; ++sp) {
            const unsigned short* SBs = SB + sp * SSTR;
            float a0[10], a1[10];
#pragma unroll
            for (int n = 0; n < 10; ++n) { a0[n] = 0.0f; a1[n] = 0.0f; }
#pragma unroll
            for (int c8 = 0; c8 < 4; ++c8) {
                const H8 wv0 = *(const H8*)(w0 + (c8 << 3));
                const H8 wv1 = *(const H8*)(w1 + (c8 << 3));
#pragma unroll
                for (int n = 0; n < 10; ++n) {
                    const H8 sv = *(const H8*)(SBs + SO(n, cb + (c8 << 3)));
                    a0[n] = dot4(sv, wv0, a0[n]);
                    a1[n] = dot4(sv, wv1, a1[n]);
                }
            }
#pragma unroll
            for (int n = 0; n < 10; ++n) {
                a0[n] += __shfl_xor(a0[n], 1);
                a1[n] += __shfl_xor(a1[n], 1);
            }
            float* yr = (float*)(XB + sp * XSTR) + (kh ? o1 : o0) * 11;
            const float* src = kh ? a1 : a0;
#pragma unroll
            for (int n = 0; n < 10; ++n) yr[n] = src[n];
        }
    }
    for (int tt = tl; tt < 560; tt += 256) {
        const int sp = (tt >= 280) ? 1 : 0;
        const int t2 = tt - sp * 280;
        const int o = t2 / 40;
        const int rem = t2 - o * 40;
        const int n = rem >> 2, part = rem & 3;
        const unsigned short* wr = W16 + WDA + (o << 9) + (part << 7);
        const unsigned short* SBs = SB + sp * SSTR;
        float s = 0.0f;
#pragma unroll
        for (int j8 = 0; j8 < 16; ++j8) {
            const H8 wv2 = *(const H8*)(wr + (j8 << 3));
            const H8 sv = *(const H8*)(SBs + SO(n, (part << 7) + (j8 << 3)));
            s = dot4(sv, wv2, s);
        }
        SMf[sp * MSTR + PRD + t2] = s;
    }
    if (tl >= 216) {
        const int idx = tl - 216;           // 0..39 = 2 samples x 20 rows
        const int sp = idx / 20;
        const int r = idx - sp * 20;
        float* base = SMf + sp * MSTR + ((r < 10) ? (BSO + r * 10) : (BDO + (r - 10) * 10));
        softmax10(base);
    }
    __syncthreads();

    // ---- P7a: ys = relu(Y0 . As + b_sagg), per sample; P0 finalize ----
    {
        const float bs = b_sagg[tl];
#pragma unroll
        for (int sp = 0; sp < 2; ++sp) {
            float* yr = (float*)(XB + sp * XSTR) + tl * 11;
            const float* SMs = SMf + sp * MSTR;
            float r[10];
#pragma unroll
            for (int n = 0; n < 10; ++n) r[n] = yr[n];
            float ys[10];
#pragma unroll
            for (int m = 0; m < 10; ++m) {
                float a = bs;
#pragma unroll
                for (int n = 0; n < 10; ++n) a += r[n] * SMs[BSO + n * 10 + m];
                ys[m] = fmaxf(a, 0.0f);
            }
#pragma unroll
            for (int m = 0; m < 10; ++m) yr[m] = ys[m];
        }
    }
    if (tl >= 116) {
        const int tt = tl - 116;            // 0..139 = 2 samples x 70
        const int sp = tt / 70;
        const int t2 = tt - sp * 70;
        float* SMs = SMf + sp * MSTR;
        const float* pr = SMs + PRD + (t2 / 10) * 40 + ((t2 - (t2 / 10) * 10) << 2);
        SMs[P0O + t2] = pr[0] + pr[1] + pr[2] + pr[3];
    }
    __syncthreads();

    // ---- P7b: T = S_d + alpha_diff * relu(P0 . Ad + b_dagg), both samples ----
    if (tl < 140) {
        const int sp = tl / 70;
        const int t2 = tl - sp * 70;
        const int o = t2 / 10, m = t2 - (t2 / 10) * 10;
        float* SMs = SMf + sp * MSTR;
        float a = b_dagg[o];
#pragma unroll
        for (int n = 0; n < 10; ++n) a += SMs[P0O + o * 10 + n] * SMs[BDO + n * 10 + m];
        SMs[TTO + t2] = S_d[o * 10 + m] + aDf * fmaxf(a, 0.0f);
    }
    __syncthreads();

    // ---- P8: scene = ys . T^T, per sample -> SB f32 ----
#pragma unroll
    for (int sp = 0; sp < 2; ++sp) {
        const float* yr = (float*)(XB + sp * XSTR) + tl * 11;
        const float* SMs = SMf + sp * MSTR;
        float* SCFs = (float*)(SB + sp * SSTR);
        float r[10];
#pragma unroll
        for (int n = 0; n < 10; ++n) r[n] = yr[n];
#pragma unroll
        for (int m = 0; m < 7; ++m) {
            float a = 0.0f;
#pragma unroll
            for (int n = 0; n < 10; ++n) a += r[n] * SMs[TTO + m * 10 + n];
            SCFs[tl * 7 + m] = a;
        }
    }
    __syncthreads();

    // ---- P9+P10: v = relu(gconv(scene, w_mot)) + head partials, per sample ----
    if (tl < 128) {
        const int o = tl;
        const int cb = (o >> 4) << 5;
        float wr[32];
#pragma unroll
        for (int i4 = 0; i4 < 8; ++i4) {
            const float4 w4 = *(const float4*)(w_mot + (o << 5) + (i4 << 2));
            wr[i4 * 4 + 0] = w4.x; wr[i4 * 4 + 1] = w4.y;
            wr[i4 * 4 + 2] = w4.z; wr[i4 * 4 + 3] = w4.w;
        }
        const float bm = b_mot[o];
        const float wm = w_mean[o], wl = w_logv[o];
#pragma unroll
        for (int sp = 0; sp < 2; ++sp) {
            const float* SCFs = (float*)(SB + sp * SSTR);
            float mu_p[7], lv_p[7];
#pragma unroll
            for (int s = 0; s < 7; ++s) {
                float a = bm;
#pragma unroll
                for (int i = 0; i < 32; ++i) a += wr[i] * SCFs[(cb + i) * 7 + s];
                const float v = fmaxf(a, 0.0f);
                mu_p[s] = v * wm; lv_p[s] = v * wl;
            }
#pragma unroll
            for (int stp = 1; stp < 64; stp <<= 1)
#pragma unroll
                for (int s = 0; s < 7; ++s) {
                    mu_p[s] += __shfl_xor(mu_p[s], stp);
                    lv_p[s] += __shfl_xor(lv_p[s], stp);
                }
            if ((tl & 63) == 0) {
                const int w = tl >> 6;
                float* SMs = SMf + sp * MSTR;
#pragma unroll
                for (int s = 0; s < 7; ++s) {
                    SMs[MUO + w * 14 + s]     = mu_p[s];
                    SMs[MUO + w * 14 + 7 + s] = lv_p[s];
                }
            }
        }
    }
    __syncthreads();

    // ---- P11: reparameterize + writes, both samples ----
    if (tl < 64) {
#pragma unroll
        for (int sp = 0; sp < 2; ++sp) {
            const float* SMs = SMf + sp * MSTR;
            const long bb2 = sp ? b1 : b0;
            float sc = 0.0f;
            if (tl < 7) {
                const float mu = b_mean[0] + SMs[MUO + tl] + SMs[MUO + 14 + tl];
                const float lv = b_logv[0] + SMs[MUO + 7 + tl] + SMs[MUO + 21 + tl];
                const float sd = __expf(0.5f * lv);
                sc = mu + sd * esp[bb2 * 7 + tl];
                out[(long)B + bb2 * 7 + tl]     = mu;
                out[(long)B * 8 + bb2 * 7 + tl] = sd;
            }
#pragma unroll
            for (int stp = 1; stp < 8; stp <<= 1) sc += __shfl_xor(sc, stp);
            if (tl == 0) out[bb2] = sc;
        }
    }
}

extern "C" void kernel_launch(void* const* d_in, const int* in_sizes, int n_in,
                              void* d_out, int out_size, void* d_ws, size_t ws_size,
                              hipStream_t stream) {
    (void)n_in; (void)out_size; (void)d_ws; (void)ws_size;
    const int B = in_sizes[0] / 10240;
    if (B <= 0) return;

    cvt_w<<<dim3((WTOT / 2 + 255) / 256), dim3(256), 0, stream>>>(
        (const float*)d_in[2],  (const float*)d_in[4],  (const float*)d_in[6],
        (const float*)d_in[7],  (const float*)d_in[10], (const float*)d_in[12],
        (const float*)d_in[13], (const float*)d_in[16]);

    xcvt<<<dim3(B), dim3(256), 0, stream>>>((const float*)d_in[0], B);

    hgcn_fused<<<dim3((B + 1) / 2), dim3(256), 0, stream>>>(
        (const float*)d_in[1],  (const float*)d_in[3],  (const float*)d_in[5],
        (const float*)d_in[8],  (const float*)d_in[9],  (const float*)d_in[11],
        (const float*)d_in[14], (const float*)d_in[15], (const float*)d_in[17],
        (const float*)d_in[18], (const float*)d_in[19], (const float*)d_in[20],
        (const float*)d_in[21], (const float*)d_in[22], (const float*)d_in[23],
        (const float*)d_in[24], (const float*)d_in[25],
        (float*)d_out, B);
}

// Round 12
// 196.508 us; speedup vs baseline: 1.1809x; 1.1809x over previous
//
#include <hip/hip_runtime.h>

// f16 vector types
typedef _Float16 h2 __attribute__((ext_vector_type(2)));
typedef __fp16   h2n __attribute__((ext_vector_type(2)));   // builtin native
typedef __fp16   h8n __attribute__((ext_vector_type(8)));   // MFMA operand
typedef float    f32x4 __attribute__((ext_vector_type(4))); // MFMA accum
struct alignas(16) H8 { h2 a, b, c, d; };          // 8 halves = one b128
struct alignas(8)  U2 { unsigned int x, y; };      // one b64

static __device__ __forceinline__ f32x4 mfma16(const H8& A, const H8& B, f32x4 C) {
    return __builtin_amdgcn_mfma_f32_16x16x32_f16(
        __builtin_bit_cast(h8n, A), __builtin_bit_cast(h8n, B), C, 0, 0, 0);
}

static __device__ __forceinline__ float dot2(h2 a, h2 b, float c) {
#if __has_builtin(__builtin_amdgcn_fdot2)
    return __builtin_amdgcn_fdot2(__builtin_bit_cast(h2n, a),
                                  __builtin_bit_cast(h2n, b), c, false);
#else
    return c + (float)a[0] * (float)b[0] + (float)a[1] * (float)b[1];
#endif
}
static __device__ __forceinline__ float dot4(const H8& x, const H8& w, float c) {
    return dot2(x.d, w.d, dot2(x.c, w.c, dot2(x.b, w.b, dot2(x.a, w.a, c))));
}
static __device__ __forceinline__ h2 pk(float a, float b) {
#if __has_builtin(__builtin_amdgcn_cvt_pkrtz)
    return __builtin_bit_cast(h2, __builtin_amdgcn_cvt_pkrtz(a, b));
#else
    h2 r; r[0] = (_Float16)a; r[1] = (_Float16)b; return r;
#endif
}
static __device__ __forceinline__ float fast_tanh(float v) {
    return 1.0f - 2.0f / (__expf(2.0f * v) + 1.0f);
}
static __device__ __forceinline__ void softmax10(float* row) {
    float mx = row[0];
#pragma unroll
    for (int i = 1; i < 10; ++i) mx = fmaxf(mx, row[i]);
    float e[10]; float sm = 0.0f;
#pragma unroll
    for (int i = 0; i < 10; ++i) { e[i] = __expf(row[i] - mx); sm += e[i]; }
    const float inv = 1.0f / sm;
#pragma unroll
    for (int i = 0; i < 10; ++i) row[i] = e[i] * inv;
}

// ---- f16 weight cache (device global, rewritten every launch — deterministic)
#define WST 0          // w_state [256][128]
#define WIN 32768      // w_info  [512][128]
#define WQS 98304      // wq_s    [128][64]
#define WKS 106496     // wk_s    [128][64]
#define WSA 114688     // w_sagg  [256][64]
#define WQD 131072     // wq_d    [128][512]
#define WKD 196608     // wk_d    [128][512]
#define WDA 262144     // w_dagg  [7][512]
#define WTOT 265728
__device__ __align__(16) unsigned short W16[WTOT];

__global__ __launch_bounds__(256) void cvt_w(
        const float* __restrict__ ws,  const float* __restrict__ wi,
        const float* __restrict__ wqs, const float* __restrict__ wks,
        const float* __restrict__ wsa, const float* __restrict__ wqd,
        const float* __restrict__ wkd, const float* __restrict__ wda) {
    const int i2 = (blockIdx.x * 256 + threadIdx.x) * 2;
    if (i2 >= WTOT) return;
    const float* src; int off;
    if      (i2 < WIN) { src = ws;  off = WST; }
    else if (i2 < WQS) { src = wi;  off = WIN; }
    else if (i2 < WKS) { src = wqs; off = WQS; }
    else if (i2 < WSA) { src = wks; off = WKS; }
    else if (i2 < WQD) { src = wsa; off = WSA; }
    else if (i2 < WKD) { src = wqd; off = WQD; }
    else if (i2 < WDA) { src = wkd; off = WKD; }
    else               { src = wda; off = WDA; }
    const float a = src[i2 - off], b2 = src[i2 - off + 1];
    *(unsigned int*)(W16 + i2) = __builtin_bit_cast(unsigned int, pk(a, b2));
}

// ---------------- LDS layout (2 samples/block) ----------------
// Per sample: XB region 5632 shorts (state [10][260] -> qT 4x[10][136] ->
//             Y0/ys f32 [256][11]); SB region 5840 shorts (shot [10][584] ->
//             sceneT f32 [7][264]); SMf region 816 f32.
// Totals: XB 22528 B + SB 23360 B + SMf 6528 B = 52416 B -> 3 blocks/CU.
#define XSTR 5632
#define SSTR 5840
#define MSTR 816
#define SO(n,c)  ((n)*584  + (c))
#define STO(n,c) ((n)*260  + (c))
#define SCT 264            // sceneT row stride in f32 (rows 8 banks apart)

#define QST 0              // qsT [10][136] f16
#define KST 1360
#define QDT 2720
#define KDT 4080
// SMf per-sample layout
#define RED2 0             // tanh wave partials [4][17]
#define ASTA 68            // A_sta [10][10]
#define BSO  168           // Bs/As [10][10]
#define BDO  268           // Bd/Ad [10][10]
#define PRD  368           // w_dagg partials [280]
#define P0O  648           // P0 [7][10]
#define TTO  718           // T  [7][10]
#define MUO  788           // head partials [2 waves][14]

#define RSQRT128 0.08838834764831843f

__global__ __launch_bounds__(256, 3)
void hgcn_fused(const float* __restrict__ x,      const float* __restrict__ esp,
                const float* __restrict__ b_state,const float* __restrict__ b_info,
                const float* __restrict__ C_s,    const float* __restrict__ alpha_s,
                const float* __restrict__ b_sagg, const float* __restrict__ C_d,
                const float* __restrict__ alpha_d,const float* __restrict__ b_dagg,
                const float* __restrict__ S_d,    const float* __restrict__ alpha_dif,
                const float* __restrict__ w_mot,  const float* __restrict__ b_mot,
                const float* __restrict__ w_mean, const float* __restrict__ b_mean,
                const float* __restrict__ w_logv, const float* __restrict__ b_logv,
                float* __restrict__ out, int B)
{
    __shared__ __align__(16) unsigned short XB[2 * XSTR];
    __shared__ __align__(16) unsigned short SB[2 * SSTR];
    __shared__ __align__(16) float SMf[2 * MSTR];

    const int tl = threadIdx.x;
    const long b0 = (long)blockIdx.x * 2;
    const long b1 = (b0 + 1 < B) ? (b0 + 1) : b0;
    const int wv = tl >> 6, ln = tl & 63;
    const int ar = ln & 15;                 // MFMA A-row / D-col lane index
    const int bn = (ar < 10) ? ar : 9;      // clamped node for B-frags
    const int kq = ln >> 4;                 // k-octet selector (0..3)

    const float aS  = alpha_s[0];
    const float aD  = alpha_d[0];
    const float aDf = alpha_dif[0];

    // Zero A_sta early (read only after two barriers below).
    if (tl < 100) { SMf[ASTA + tl] = 0.0f; SMf[MSTR + ASTA + tl] = 0.0f; }

    // ---- P1 (MFMA, 2 samples): state + info gconvs, K=128/group.
    // B-frags direct from global x (stride-10 dwords, L1-shared across the 10
    // node-lanes; x is L3-resident in the replay regime). A-frags (W16) loaded
    // once, used for both samples.
    {
        const float* xg0 = x + b0 * 10240 + bn;
        const float* xg1 = x + b1 * 10240 + bn;
        const f32x4 z = {0.0f, 0.0f, 0.0f, 0.0f};
        f32x4 stk[2][2][2];
#pragma unroll
        for (int sp = 0; sp < 2; ++sp)
#pragma unroll
            for (int gi = 0; gi < 2; ++gi)
#pragma unroll
                for (int mt = 0; mt < 2; ++mt) stk[sp][gi][mt] = z;
#pragma unroll
        for (int gi = 0; gi < 2; ++gi) {
            const int grp = (wv << 1) + gi;
            const int cb = grp << 7;
            f32x4 inf[2][4];
#pragma unroll
            for (int sp = 0; sp < 2; ++sp)
#pragma unroll
                for (int mt = 0; mt < 4; ++mt) inf[sp][mt] = z;
#pragma unroll
            for (int kt = 0; kt < 4; ++kt) {
                const int ka = cb + (kt << 5) + (kq << 3);
                float xv0[8], xv1[8];
#pragma unroll
                for (int j = 0; j < 8; ++j) {
                    xv0[j] = xg0[(ka + j) * 10];
                    xv1[j] = xg1[(ka + j) * 10];
                }
                H8 bf0, bf1;
                bf0.a = pk(xv0[0], xv0[1]); bf0.b = pk(xv0[2], xv0[3]);
                bf0.c = pk(xv0[4], xv0[5]); bf0.d = pk(xv0[6], xv0[7]);
                bf1.a = pk(xv1[0], xv1[1]); bf1.b = pk(xv1[2], xv1[3]);
                bf1.c = pk(xv1[4], xv1[5]); bf1.d = pk(xv1[6], xv1[7]);
                const int ko = (kt << 5) + (kq << 3);
                const unsigned short* wsrow = W16 + WST + (((grp << 5) + ar) << 7) + ko;
                const unsigned short* wirow = W16 + WIN + (((grp << 6) + ar) << 7) + ko;
                const H8 as0 = *(const H8*)(wsrow);
                const H8 as1 = *(const H8*)(wsrow + (16 << 7));
                const H8 ai0 = *(const H8*)(wirow);
                const H8 ai1 = *(const H8*)(wirow + (16 << 7));
                const H8 ai2 = *(const H8*)(wirow + (32 << 7));
                const H8 ai3 = *(const H8*)(wirow + (48 << 7));
                stk[0][gi][0] = mfma16(as0, bf0, stk[0][gi][0]);
                stk[0][gi][1] = mfma16(as1, bf0, stk[0][gi][1]);
                stk[1][gi][0] = mfma16(as0, bf1, stk[1][gi][0]);
                stk[1][gi][1] = mfma16(as1, bf1, stk[1][gi][1]);
                inf[0][0] = mfma16(ai0, bf0, inf[0][0]);
                inf[0][1] = mfma16(ai1, bf0, inf[0][1]);
                inf[0][2] = mfma16(ai2, bf0, inf[0][2]);
                inf[0][3] = mfma16(ai3, bf0, inf[0][3]);
                inf[1][0] = mfma16(ai0, bf1, inf[1][0]);
                inf[1][1] = mfma16(ai1, bf1, inf[1][1]);
                inf[1][2] = mfma16(ai2, bf1, inf[1][2]);
                inf[1][3] = mfma16(ai3, bf1, inf[1][3]);
            }
            if (ar < 10) {
#pragma unroll
                for (int sp = 0; sp < 2; ++sp) {
                    unsigned short* SBs = SB + sp * SSTR;
#pragma unroll
                    for (int mt = 0; mt < 4; ++mt) {
                        U2 u;
                        u.x = __builtin_bit_cast(unsigned int, pk(inf[sp][mt][0], inf[sp][mt][1]));
                        u.y = __builtin_bit_cast(unsigned int, pk(inf[sp][mt][2], inf[sp][mt][3]));
                        *(U2*)(SBs + SO(ar, (grp << 6) + (mt << 4) + (kq << 2))) = u;
                    }
                }
            }
        }
        if (ar < 10) {
#pragma unroll
            for (int sp = 0; sp < 2; ++sp) {
                unsigned short* XBs = XB + sp * XSTR;
#pragma unroll
                for (int gi = 0; gi < 2; ++gi) {
#pragma unroll
                    for (int mt = 0; mt < 2; ++mt) {
                        U2 u;
                        u.x = __builtin_bit_cast(unsigned int, pk(stk[sp][gi][mt][0], stk[sp][gi][mt][1]));
                        u.y = __builtin_bit_cast(unsigned int, pk(stk[sp][gi][mt][2], stk[sp][gi][mt][3]));
                        *(U2*)(XBs + STO(ar, (((wv << 1) + gi) << 5) + (mt << 4) + (kq << 2))) = u;
                    }
                }
            }
        }
    }
    __syncthreads();

    // ---- P2: tanh diffs, per sample, shfl butterfly ----
    {
        const float bb = b_state[tl];
#pragma unroll
        for (int sp = 0; sp < 2; ++sp) {
            const unsigned short* XBs = XB + sp * XSTR;
            float* SMs = SMf + sp * MSTR;
            float st[10];
#pragma unroll
            for (int n = 0; n < 10; ++n) {
                const unsigned short u = XBs[STO(n, tl)];
                st[n] = fmaxf((float)__builtin_bit_cast(_Float16, u) + bb, 0.0f);
            }
            float red[17];
#pragma unroll
            for (int p = 0; p < 17; ++p) {
                const int n = (p < 9) ? p : (p - 9);
                const int m = (p < 9) ? (p + 1) : (p - 9 + 2);
                red[p] = fast_tanh(st[n] - st[m]);
            }
#pragma unroll
            for (int stp = 1; stp < 64; stp <<= 1)
#pragma unroll
                for (int p = 0; p < 17; ++p) red[p] += __shfl_xor(red[p], stp);
            if (ln == 0) {
#pragma unroll
                for (int p = 0; p < 17; ++p) SMs[RED2 + wv * 17 + p] = red[p];
            }
        }
    }
    __syncthreads();

    // ---- P2b: assemble A_sta (both samples); zeroing done at kernel start ----
    if (tl < 17) {
#pragma unroll
        for (int sp = 0; sp < 2; ++sp) {
            float* SMs = SMf + sp * MSTR;
            const float s = (SMs[RED2 + tl] + SMs[RED2 + 17 + tl] +
                             SMs[RED2 + 34 + tl] + SMs[RED2 + 51 + tl]) * (1.0f / 256.0f);
            const int n = (tl < 9) ? tl : (tl - 9);
            const int m = (tl < 9) ? (tl + 1) : (tl - 9 + 2);
            SMs[ASTA + n * 10 + m] = s;
            SMs[ASTA + m * 10 + n] = -s;
        }
    } else if (tl < 27) {
        const int n = tl - 17;
        SMf[ASTA + n * 10 + n] = 1.0f;
        SMf[MSTR + ASTA + n * 10 + n] = 1.0f;
    }
    __syncthreads();

    // ---- P3: shot = relu(S0 . A_sta + b_info), per sample ----
    {
        const int c0 = tl << 1;
        const float bi0 = b_info[c0], bi1 = b_info[c0 + 1];
#pragma unroll
        for (int sp = 0; sp < 2; ++sp) {
            unsigned short* SBs = SB + sp * SSTR;
            const float* SMs = SMf + sp * MSTR;
            float sa[10], sb2[10];
#pragma unroll
            for (int n = 0; n < 10; ++n) {
                const h2 v = __builtin_bit_cast(h2, *(const unsigned int*)(SBs + SO(n, c0)));
                sa[n] = (float)v[0]; sb2[n] = (float)v[1];
            }
            unsigned int o10[10];
#pragma unroll
            for (int m = 0; m < 10; ++m) {
                float t0 = bi0, t1 = bi1;
#pragma unroll
                for (int n = 0; n < 10; ++n) {
                    const float a = SMs[ASTA + n * 10 + m];
                    t0 += sa[n] * a; t1 += sb2[n] * a;
                }
                o10[m] = __builtin_bit_cast(unsigned int, pk(fmaxf(t0, 0.0f), fmaxf(t1, 0.0f)));
            }
#pragma unroll
            for (int m = 0; m < 10; ++m)
                *(unsigned int*)(SBs + SO(m, c0)) = o10[m];
        }
    }
    __syncthreads();

    // ---- P4 (MFMA, 2 samples): q_d/k_d (K=512) + q_s/k_s (grouped K=64) ----
    {
        const f32x4 z = {0.0f, 0.0f, 0.0f, 0.0f};
        f32x4 qa[2][2], ka4[2][2];
#pragma unroll
        for (int sp = 0; sp < 2; ++sp)
#pragma unroll
            for (int h = 0; h < 2; ++h) { qa[sp][h] = z; ka4[sp][h] = z; }
        const unsigned short* wq0 = W16 + WQD + (((wv << 5) + ar) << 9);
        const unsigned short* wk0 = W16 + WKD + (((wv << 5) + ar) << 9);
        for (int kt = 0; kt < 16; ++kt) {
            const int ko = (kt << 5) + (kq << 3);
            const H8 bf0 = *(const H8*)(SB + SO(bn, ko));
            const H8 bf1 = *(const H8*)(SB + SSTR + SO(bn, ko));
            const H8 aq0 = *(const H8*)(wq0 + ko);
            const H8 aq1 = *(const H8*)(wq0 + (16 << 9) + ko);
            const H8 ak0 = *(const H8*)(wk0 + ko);
            const H8 ak1 = *(const H8*)(wk0 + (16 << 9) + ko);
            qa[0][0] = mfma16(aq0, bf0, qa[0][0]);
            qa[0][1] = mfma16(aq1, bf0, qa[0][1]);
            ka4[0][0] = mfma16(ak0, bf0, ka4[0][0]);
            ka4[0][1] = mfma16(ak1, bf0, ka4[0][1]);
            qa[1][0] = mfma16(aq0, bf1, qa[1][0]);
            qa[1][1] = mfma16(aq1, bf1, qa[1][1]);
            ka4[1][0] = mfma16(ak0, bf1, ka4[1][0]);
            ka4[1][1] = mfma16(ak1, bf1, ka4[1][1]);
        }
        if (ar < 10) {
            const int oc = (wv << 5) + (kq << 2);
#pragma unroll
            for (int sp = 0; sp < 2; ++sp) {
                unsigned short* XBs = XB + sp * XSTR;
                U2 u;
                u.x = __builtin_bit_cast(unsigned int, pk(qa[sp][0][0], qa[sp][0][1]));
                u.y = __builtin_bit_cast(unsigned int, pk(qa[sp][0][2], qa[sp][0][3]));
                *(U2*)(XBs + QDT + ar * 136 + oc) = u;
                u.x = __builtin_bit_cast(unsigned int, pk(qa[sp][1][0], qa[sp][1][1]));
                u.y = __builtin_bit_cast(unsigned int, pk(qa[sp][1][2], qa[sp][1][3]));
                *(U2*)(XBs + QDT + ar * 136 + oc + 16) = u;
                u.x = __builtin_bit_cast(unsigned int, pk(ka4[sp][0][0], ka4[sp][0][1]));
                u.y = __builtin_bit_cast(unsigned int, pk(ka4[sp][0][2], ka4[sp][0][3]));
                *(U2*)(XBs + KDT + ar * 136 + oc) = u;
                u.x = __builtin_bit_cast(unsigned int, pk(ka4[sp][1][0], ka4[sp][1][1]));
                u.y = __builtin_bit_cast(unsigned int, pk(ka4[sp][1][2], ka4[sp][1][3]));
                *(U2*)(XBs + KDT + ar * 136 + oc + 16) = u;
            }
        }
#pragma unroll
        for (int gi = 0; gi < 2; ++gi) {
            const int gs = (wv << 1) + gi;
            f32x4 qs[2], ks[2];
            qs[0] = z; qs[1] = z; ks[0] = z; ks[1] = z;
#pragma unroll
            for (int kt = 0; kt < 2; ++kt) {
                const int ko = (kt << 5) + (kq << 3);
                const H8 aq = *(const H8*)(W16 + WQS + (((gs << 4) + ar) << 6) + ko);
                const H8 ak = *(const H8*)(W16 + WKS + (((gs << 4) + ar) << 6) + ko);
                const H8 bf0 = *(const H8*)(SB + SO(bn, (gs << 6) + ko));
                const H8 bf1 = *(const H8*)(SB + SSTR + SO(bn, (gs << 6) + ko));
                qs[0] = mfma16(aq, bf0, qs[0]);
                ks[0] = mfma16(ak, bf0, ks[0]);
                qs[1] = mfma16(aq, bf1, qs[1]);
                ks[1] = mfma16(ak, bf1, ks[1]);
            }
            if (ar < 10) {
                const int oc = (gs << 4) + (kq << 2);
#pragma unroll
                for (int sp = 0; sp < 2; ++sp) {
                    unsigned short* XBs = XB + sp * XSTR;
                    U2 u;
                    u.x = __builtin_bit_cast(unsigned int, pk(qs[sp][0], qs[sp][1]));
                    u.y = __builtin_bit_cast(unsigned int, pk(qs[sp][2], qs[sp][3]));
                    *(U2*)(XBs + QST + ar * 136 + oc) = u;
                    u.x = __builtin_bit_cast(unsigned int, pk(ks[sp][0], ks[sp][1]));
                    u.y = __builtin_bit_cast(unsigned int, pk(ks[sp][2], ks[sp][3]));
                    *(U2*)(XBs + KST + ar * 136 + oc) = u;
                }
            }
        }
    }
    __syncthreads();

    // ---- P5: Bs|Bd logits, both samples ----
    if (tl < 200) {
        const int t = (tl < 100) ? tl : (tl - 100);
        const int n = t / 10, m = t - (t / 10) * 10;
        const int d = (n > m) ? (n - m) : (m - n);
        const float band = (d <= 3) ? 1.0f : 0.0f;
        const float Cv = (tl < 100) ? C_s[n * 10 + m] : C_d[n * 10 + m];
        const float al = (tl < 100) ? aS : aD;
        const int qoff = ((tl < 100) ? QST : QDT) + n * 136;
        const int koff = ((tl < 100) ? KST : KDT) + m * 136;
        const int dsto = (tl < 100) ? (BSO + t) : (BDO + t);
#pragma unroll
        for (int sp = 0; sp < 2; ++sp) {
            const unsigned short* q = XB + sp * XSTR + qoff;
            const unsigned short* k = XB + sp * XSTR + koff;
            float s = 0.0f;
#pragma unroll
            for (int c8 = 0; c8 < 16; ++c8) {
                const H8 qv = *(const H8*)(q + (c8 << 3));
                const H8 kv = *(const H8*)(k + (c8 << 3));
                s = dot4(qv, kv, s);
            }
            SMf[sp * MSTR + dsto] = al * (s * RSQRT128) + Cv + band;
        }
    }
    __syncthreads();

    // ---- P6: Y0 + PRD partials + softmaxes, both samples ----
    {
        const int p = tl >> 1, kh = tl & 1;
        const int gs = p >> 4, ls = p & 15;
        const int o0 = (gs << 5) + ls, o1 = o0 + 16;
        const int cb = (gs << 6) + (kh << 5);
        const unsigned short* w0 = W16 + WSA + (o0 << 6) + (kh << 5);
        const unsigned short* w1 = W16 + WSA + (o1 << 6) + (kh << 5);
#pragma unroll
        for (int sp = 0; sp < 2; ++sp) {
            const unsigned short* SBs = SB + sp * SSTR;
            float a0[10], a1[10];
#pragma unroll
            for (int n = 0; n < 10; ++n) { a0[n] = 0.0f; a1[n] = 0.0f; }
#pragma unroll
            for (int c8 = 0; c8 < 4; ++c8) {
                const H8 wv0 = *(const H8*)(w0 + (c8 << 3));
                const H8 wv1 = *(const H8*)(w1 + (c8 << 3));
#pragma unroll
                for (int n = 0; n < 10; ++n) {
                    const H8 sv = *(const H8*)(SBs + SO(n, cb + (c8 << 3)));
                    a0[n] = dot4(sv, wv0, a0[n]);
                    a1[n] = dot4(sv, wv1, a1[n]);
                }
            }
#pragma unroll
            for (int n = 0; n < 10; ++n) {
                a0[n] += __shfl_xor(a0[n], 1);
                a1[n] += __shfl_xor(a1[n], 1);
            }
            float* yr = (float*)(XB + sp * XSTR) + (kh ? o1 : o0) * 11;
            const float* src = kh ? a1 : a0;
#pragma unroll
            for (int n = 0; n < 10; ++n) yr[n] = src[n];
        }
    }
    for (int tt = tl; tt < 560; tt += 256) {
        const int sp = (tt >= 280) ? 1 : 0;
        const int t2 = tt - sp * 280;
        const int o = t2 / 40;
        const int rem = t2 - o * 40;
        const int n = rem >> 2, part = rem & 3;
        const unsigned short* wr = W16 + WDA + (o << 9) + (part << 7);
        const unsigned short* SBs = SB + sp * SSTR;
        float s = 0.0f;
#pragma unroll
        for (int j8 = 0; j8 < 16; ++j8) {
            const H8 wv2 = *(const H8*)(wr + (j8 << 3));
            const H8 sv = *(const H8*)(SBs + SO(n, (part << 7) + (j8 << 3)));
            s = dot4(sv, wv2, s);
        }
        SMf[sp * MSTR + PRD + t2] = s;
    }
    if (tl >= 216) {
        const int idx = tl - 216;           // 0..39 = 2 samples x 20 rows
        const int sp = idx / 20;
        const int r = idx - sp * 20;
        float* base = SMf + sp * MSTR + ((r < 10) ? (BSO + r * 10) : (BDO + (r - 10) * 10));
        softmax10(base);
    }
    __syncthreads();

    // ---- P7a: ys = relu(Y0 . As + b_sagg), per sample; P0 finalize ----
    {
        const float bs = b_sagg[tl];
#pragma unroll
        for (int sp = 0; sp < 2; ++sp) {
            float* yr = (float*)(XB + sp * XSTR) + tl * 11;
            const float* SMs = SMf + sp * MSTR;
            float r[10];
#pragma unroll
            for (int n = 0; n < 10; ++n) r[n] = yr[n];
            float ys[10];
#pragma unroll
            for (int m = 0; m < 10; ++m) {
                float a = bs;
#pragma unroll
                for (int n = 0; n < 10; ++n) a += r[n] * SMs[BSO + n * 10 + m];
                ys[m] = fmaxf(a, 0.0f);
            }
#pragma unroll
            for (int m = 0; m < 10; ++m) yr[m] = ys[m];
        }
    }
    if (tl >= 116) {
        const int tt = tl - 116;            // 0..139 = 2 samples x 70
        const int sp = tt / 70;
        const int t2 = tt - sp * 70;
        float* SMs = SMf + sp * MSTR;
        const float* pr = SMs + PRD + (t2 / 10) * 40 + ((t2 - (t2 / 10) * 10) << 2);
        SMs[P0O + t2] = pr[0] + pr[1] + pr[2] + pr[3];
    }
    __syncthreads();

    // ---- P7b: T = S_d + alpha_diff * relu(P0 . Ad + b_dagg), both samples ----
    if (tl < 140) {
        const int sp = tl / 70;
        const int t2 = tl - sp * 70;
        const int o = t2 / 10, m = t2 - (t2 / 10) * 10;
        float* SMs = SMf + sp * MSTR;
        float a = b_dagg[o];
#pragma unroll
        for (int n = 0; n < 10; ++n) a += SMs[P0O + o * 10 + n] * SMs[BDO + n * 10 + m];
        SMs[TTO + t2] = S_d[o * 10 + m] + aDf * fmaxf(a, 0.0f);
    }
    __syncthreads();

    // ---- P8: sceneT[m][c] = sum_n ys[c][n] * T[m][n], per sample -> SB f32 ----
#pragma unroll
    for (int sp = 0; sp < 2; ++sp) {
        const float* yr = (float*)(XB + sp * XSTR) + tl * 11;
        const float* SMs = SMf + sp * MSTR;
        float* SCFs = (float*)(SB + sp * SSTR);
        float r[10];
#pragma unroll
        for (int n = 0; n < 10; ++n) r[n] = yr[n];
#pragma unroll
        for (int m = 0; m < 7; ++m) {
            float a = 0.0f;
#pragma unroll
            for (int n = 0; n < 10; ++n) a += r[n] * SMs[TTO + m * 10 + n];
            SCFs[m * SCT + tl] = a;      // transposed: row m contiguous over c
        }
    }
    __syncthreads();

    // ---- P9+P10: v = relu(gconv(scene, w_mot)) + head partials, per sample.
    // sceneT rows contiguous -> 8x float4 loads per s instead of 32 scalars.
    if (tl < 128) {
        const int o = tl;
        const int cb = (o >> 4) << 5;
        float wr[32];
#pragma unroll
        for (int i4 = 0; i4 < 8; ++i4) {
            const float4 w4 = *(const float4*)(w_mot + (o << 5) + (i4 << 2));
            wr[i4 * 4 + 0] = w4.x; wr[i4 * 4 + 1] = w4.y;
            wr[i4 * 4 + 2] = w4.z; wr[i4 * 4 + 3] = w4.w;
        }
        const float bm = b_mot[o];
        const float wm = w_mean[o], wl = w_logv[o];
#pragma unroll
        for (int sp = 0; sp < 2; ++sp) {
            const float* SCFs = (float*)(SB + sp * SSTR);
            float mu_p[7], lv_p[7];
#pragma unroll
            for (int s = 0; s < 7; ++s) {
                float a = bm;
                const float4* rp = (const float4*)(SCFs + s * SCT + cb);
#pragma unroll
                for (int i = 0; i < 8; ++i) {
                    const float4 v4 = rp[i];
                    a += wr[4 * i] * v4.x + wr[4 * i + 1] * v4.y +
                         wr[4 * i + 2] * v4.z + wr[4 * i + 3] * v4.w;
                }
                const float v = fmaxf(a, 0.0f);
                mu_p[s] = v * wm; lv_p[s] = v * wl;
            }
#pragma unroll
            for (int stp = 1; stp < 64; stp <<= 1)
#pragma unroll
                for (int s = 0; s < 7; ++s) {
                    mu_p[s] += __shfl_xor(mu_p[s], stp);
                    lv_p[s] += __shfl_xor(lv_p[s], stp);
                }
            if ((tl & 63) == 0) {
                const int w = tl >> 6;
                float* SMs = SMf + sp * MSTR;
#pragma unroll
                for (int s = 0; s < 7; ++s) {
                    SMs[MUO + w * 14 + s]     = mu_p[s];
                    SMs[MUO + w * 14 + 7 + s] = lv_p[s];
                }
            }
        }
    }
    __syncthreads();

    // ---- P11: reparameterize + writes, both samples ----
    if (tl < 64) {
#pragma unroll
        for (int sp = 0; sp < 2; ++sp) {
            const float* SMs = SMf + sp * MSTR;
            const long bb2 = sp ? b1 : b0;
            float sc = 0.0f;
            if (tl < 7) {
                const float mu = b_mean[0] + SMs[MUO + tl] + SMs[MUO + 14 + tl];
                const float lv = b_logv[0] + SMs[MUO + 7 + tl] + SMs[MUO + 21 + tl];
                const float sd = __expf(0.5f * lv);
                sc = mu + sd * esp[bb2 * 7 + tl];
                out[(long)B + bb2 * 7 + tl]     = mu;
                out[(long)B * 8 + bb2 * 7 + tl] = sd;
            }
#pragma unroll
            for (int stp = 1; stp < 8; stp <<= 1) sc += __shfl_xor(sc, stp);
            if (tl == 0) out[bb2] = sc;
        }
    }
}

extern "C" void kernel_launch(void* const* d_in, const int* in_sizes, int n_in,
                              void* d_out, int out_size, void* d_ws, size_t ws_size,
                              hipStream_t stream) {
    (void)n_in; (void)out_size; (void)d_ws; (void)ws_size;
    const int B = in_sizes[0] / 10240;
    if (B <= 0) return;

    cvt_w<<<dim3((WTOT / 2 + 255) / 256), dim3(256), 0, stream>>>(
        (const float*)d_in[2],  (const float*)d_in[4],  (const float*)d_in[6],
        (const float*)d_in[7],  (const float*)d_in[10], (const float*)d_in[12],
        (const float*)d_in[13], (const float*)d_in[16]);

    hgcn_fused<<<dim3((B + 1) / 2), dim3(256), 0, stream>>>(
        (const float*)d_in[0],  (const float*)d_in[1],  (const float*)d_in[3],
        (const float*)d_in[5],  (const float*)d_in[8],  (const float*)d_in[9],
        (const float*)d_in[11], (const float*)d_in[14], (const float*)d_in[15],
        (const float*)d_in[17], (const float*)d_in[18], (const float*)d_in[19],
        (const float*)d_in[20], (const float*)d_in[21], (const float*)d_in[22],
        (const float*)d_in[23], (const float*)d_in[24], (const float*)d_in[25],
        (float*)d_out, B);
}

// Round 13
// 195.758 us; speedup vs baseline: 1.1854x; 1.0038x over previous
//
#include <hip/hip_runtime.h>

// f16 vector types
typedef _Float16 h2 __attribute__((ext_vector_type(2)));
typedef __fp16   h2n __attribute__((ext_vector_type(2)));   // builtin native
typedef __fp16   h8n __attribute__((ext_vector_type(8)));   // MFMA operand
typedef float    f32x4 __attribute__((ext_vector_type(4))); // MFMA accum
struct alignas(16) H8 { h2 a, b, c, d; };          // 8 halves = one b128
struct alignas(8)  U2 { unsigned int x, y; };      // one b64

static __device__ __forceinline__ f32x4 mfma16(const H8& A, const H8& B, f32x4 C) {
    return __builtin_amdgcn_mfma_f32_16x16x32_f16(
        __builtin_bit_cast(h8n, A), __builtin_bit_cast(h8n, B), C, 0, 0, 0);
}

static __device__ __forceinline__ float dot2(h2 a, h2 b, float c) {
#if __has_builtin(__builtin_amdgcn_fdot2)
    return __builtin_amdgcn_fdot2(__builtin_bit_cast(h2n, a),
                                  __builtin_bit_cast(h2n, b), c, false);
#else
    return c + (float)a[0] * (float)b[0] + (float)a[1] * (float)b[1];
#endif
}
static __device__ __forceinline__ float dot4(const H8& x, const H8& w, float c) {
    return dot2(x.d, w.d, dot2(x.c, w.c, dot2(x.b, w.b, dot2(x.a, w.a, c))));
}
static __device__ __forceinline__ h2 pk(float a, float b) {
#if __has_builtin(__builtin_amdgcn_cvt_pkrtz)
    return __builtin_bit_cast(h2, __builtin_amdgcn_cvt_pkrtz(a, b));
#else
    h2 r; r[0] = (_Float16)a; r[1] = (_Float16)b; return r;
#endif
}
static __device__ __forceinline__ float fast_tanh(float v) {
    return 1.0f - 2.0f / (__expf(2.0f * v) + 1.0f);
}
static __device__ __forceinline__ void softmax10(float* row) {
    float mx = row[0];
#pragma unroll
    for (int i = 1; i < 10; ++i) mx = fmaxf(mx, row[i]);
    float e[10]; float sm = 0.0f;
#pragma unroll
    for (int i = 0; i < 10; ++i) { e[i] = __expf(row[i] - mx); sm += e[i]; }
    const float inv = 1.0f / sm;
#pragma unroll
    for (int i = 0; i < 10; ++i) row[i] = e[i] * inv;
}

// ---- f16 weight cache (device global, rewritten every launch — deterministic)
#define WST 0          // w_state [256][128]
#define WIN 32768      // w_info  [512][128]
#define WQS 98304      // wq_s    [128][64]
#define WKS 106496     // wk_s    [128][64]
#define WSA 114688     // w_sagg  [256][64]
#define WQD 131072     // wq_d    [128][512]
#define WKD 196608     // wk_d    [128][512]
#define WDA 262144     // w_dagg  [7][512]
#define WTOT 265728
__device__ __align__(16) unsigned short W16[WTOT];

__global__ __launch_bounds__(256) void cvt_w(
        const float* __restrict__ ws,  const float* __restrict__ wi,
        const float* __restrict__ wqs, const float* __restrict__ wks,
        const float* __restrict__ wsa, const float* __restrict__ wqd,
        const float* __restrict__ wkd, const float* __restrict__ wda) {
    const int i2 = (blockIdx.x * 256 + threadIdx.x) * 2;
    if (i2 >= WTOT) return;
    const float* src; int off;
    if      (i2 < WIN) { src = ws;  off = WST; }
    else if (i2 < WQS) { src = wi;  off = WIN; }
    else if (i2 < WKS) { src = wqs; off = WQS; }
    else if (i2 < WSA) { src = wks; off = WKS; }
    else if (i2 < WQD) { src = wsa; off = WSA; }
    else if (i2 < WKD) { src = wqd; off = WQD; }
    else if (i2 < WDA) { src = wkd; off = WKD; }
    else               { src = wda; off = WDA; }
    const float a = src[i2 - off], b2 = src[i2 - off + 1];
    *(unsigned int*)(W16 + i2) = __builtin_bit_cast(unsigned int, pk(a, b2));
}

// ---------------- LDS layout (2 samples/block) ----------------
// Per sample: XB region 5632 shorts (state [10][260] -> qT 4x[10][136] ->
//             Y0/ys f32 [256][11]); SB region 5840 shorts (shot [10][584] ->
//             sceneT f32 [7][264]); SMf region 816 f32.
// Totals: XB 22528 B + SB 23360 B + SMf 6528 B = 52416 B -> 3 blocks/CU.
#define XSTR 5632
#define SSTR 5840
#define MSTR 816
#define SO(n,c)  ((n)*584  + (c))
#define STO(n,c) ((n)*260  + (c))
#define SCT 264            // sceneT row stride in f32 (rows 8 banks apart)

#define QST 0              // qsT [10][136] f16
#define KST 1360
#define QDT 2720
#define KDT 4080
// SMf per-sample layout
#define RED2 0             // tanh wave partials [4][17]
#define BSO  168           // Bs/As [10][10]
#define BDO  268           // Bd/Ad [10][10]
#define PRD  368           // w_dagg partials [280]
#define TTO  718           // T  [7][10]
#define MUO  788           // head partials [2 waves][14]

#define RSQRT128 0.08838834764831843f

__global__ __launch_bounds__(256, 3)
void hgcn_fused(const float* __restrict__ x,      const float* __restrict__ esp,
                const float* __restrict__ b_state,const float* __restrict__ b_info,
                const float* __restrict__ C_s,    const float* __restrict__ alpha_s,
                const float* __restrict__ b_sagg, const float* __restrict__ C_d,
                const float* __restrict__ alpha_d,const float* __restrict__ b_dagg,
                const float* __restrict__ S_d,    const float* __restrict__ alpha_dif,
                const float* __restrict__ w_mot,  const float* __restrict__ b_mot,
                const float* __restrict__ w_mean, const float* __restrict__ b_mean,
                const float* __restrict__ w_logv, const float* __restrict__ b_logv,
                float* __restrict__ out, int B)
{
    __shared__ __align__(16) unsigned short XB[2 * XSTR];
    __shared__ __align__(16) unsigned short SB[2 * SSTR];
    __shared__ __align__(16) float SMf[2 * MSTR];

    const int tl = threadIdx.x;
    const long b0 = (long)blockIdx.x * 2;
    const long b1 = (b0 + 1 < B) ? (b0 + 1) : b0;
    const int wv = tl >> 6, ln = tl & 63;
    const int ar = ln & 15;                 // MFMA A-row / D-col lane index
    const int bn = (ar < 10) ? ar : 9;      // clamped node for B-frags
    const int kq = ln >> 4;                 // k-octet selector (0..3)

    const float aS  = alpha_s[0];
    const float aD  = alpha_d[0];
    const float aDf = alpha_dif[0];

    // ---- P1 (MFMA, 2 samples): state + info gconvs, K=128/group.
    // B-frags direct from global x (stride-10 dwords, L3-resident in replay).
    // A-frags (W16) loaded once, used for both samples.
    {
        const float* xg0 = x + b0 * 10240 + bn;
        const float* xg1 = x + b1 * 10240 + bn;
        const f32x4 z = {0.0f, 0.0f, 0.0f, 0.0f};
        f32x4 stk[2][2][2];
#pragma unroll
        for (int sp = 0; sp < 2; ++sp)
#pragma unroll
            for (int gi = 0; gi < 2; ++gi)
#pragma unroll
                for (int mt = 0; mt < 2; ++mt) stk[sp][gi][mt] = z;
#pragma unroll
        for (int gi = 0; gi < 2; ++gi) {
            const int grp = (wv << 1) + gi;
            const int cb = grp << 7;
            f32x4 inf[2][4];
#pragma unroll
            for (int sp = 0; sp < 2; ++sp)
#pragma unroll
                for (int mt = 0; mt < 4; ++mt) inf[sp][mt] = z;
#pragma unroll
            for (int kt = 0; kt < 4; ++kt) {
                const int ka = cb + (kt << 5) + (kq << 3);
                float xv0[8], xv1[8];
#pragma unroll
                for (int j = 0; j < 8; ++j) {
                    xv0[j] = xg0[(ka + j) * 10];
                    xv1[j] = xg1[(ka + j) * 10];
                }
                H8 bf0, bf1;
                bf0.a = pk(xv0[0], xv0[1]); bf0.b = pk(xv0[2], xv0[3]);
                bf0.c = pk(xv0[4], xv0[5]); bf0.d = pk(xv0[6], xv0[7]);
                bf1.a = pk(xv1[0], xv1[1]); bf1.b = pk(xv1[2], xv1[3]);
                bf1.c = pk(xv1[4], xv1[5]); bf1.d = pk(xv1[6], xv1[7]);
                const int ko = (kt << 5) + (kq << 3);
                const unsigned short* wsrow = W16 + WST + (((grp << 5) + ar) << 7) + ko;
                const unsigned short* wirow = W16 + WIN + (((grp << 6) + ar) << 7) + ko;
                const H8 as0 = *(const H8*)(wsrow);
                const H8 as1 = *(const H8*)(wsrow + (16 << 7));
                const H8 ai0 = *(const H8*)(wirow);
                const H8 ai1 = *(const H8*)(wirow + (16 << 7));
                const H8 ai2 = *(const H8*)(wirow + (32 << 7));
                const H8 ai3 = *(const H8*)(wirow + (48 << 7));
                stk[0][gi][0] = mfma16(as0, bf0, stk[0][gi][0]);
                stk[0][gi][1] = mfma16(as1, bf0, stk[0][gi][1]);
                stk[1][gi][0] = mfma16(as0, bf1, stk[1][gi][0]);
                stk[1][gi][1] = mfma16(as1, bf1, stk[1][gi][1]);
                inf[0][0] = mfma16(ai0, bf0, inf[0][0]);
                inf[0][1] = mfma16(ai1, bf0, inf[0][1]);
                inf[0][2] = mfma16(ai2, bf0, inf[0][2]);
                inf[0][3] = mfma16(ai3, bf0, inf[0][3]);
                inf[1][0] = mfma16(ai0, bf1, inf[1][0]);
                inf[1][1] = mfma16(ai1, bf1, inf[1][1]);
                inf[1][2] = mfma16(ai2, bf1, inf[1][2]);
                inf[1][3] = mfma16(ai3, bf1, inf[1][3]);
            }
            if (ar < 10) {
#pragma unroll
                for (int sp = 0; sp < 2; ++sp) {
                    unsigned short* SBs = SB + sp * SSTR;
#pragma unroll
                    for (int mt = 0; mt < 4; ++mt) {
                        U2 u;
                        u.x = __builtin_bit_cast(unsigned int, pk(inf[sp][mt][0], inf[sp][mt][1]));
                        u.y = __builtin_bit_cast(unsigned int, pk(inf[sp][mt][2], inf[sp][mt][3]));
                        *(U2*)(SBs + SO(ar, (grp << 6) + (mt << 4) + (kq << 2))) = u;
                    }
                }
            }
        }
        if (ar < 10) {
#pragma unroll
            for (int sp = 0; sp < 2; ++sp) {
                unsigned short* XBs = XB + sp * XSTR;
#pragma unroll
                for (int gi = 0; gi < 2; ++gi) {
#pragma unroll
                    for (int mt = 0; mt < 2; ++mt) {
                        U2 u;
                        u.x = __builtin_bit_cast(unsigned int, pk(stk[sp][gi][mt][0], stk[sp][gi][mt][1]));
                        u.y = __builtin_bit_cast(unsigned int, pk(stk[sp][gi][mt][2], stk[sp][gi][mt][3]));
                        *(U2*)(XBs + STO(ar, (((wv << 1) + gi) << 5) + (mt << 4) + (kq << 2))) = u;
                    }
                }
            }
        }
    }
    __syncthreads();

    // ---- P2: tanh diffs, per sample, shfl butterfly -> RED2 partials ----
    {
        const float bb = b_state[tl];
#pragma unroll
        for (int sp = 0; sp < 2; ++sp) {
            const unsigned short* XBs = XB + sp * XSTR;
            float* SMs = SMf + sp * MSTR;
            float st[10];
#pragma unroll
            for (int n = 0; n < 10; ++n) {
                const unsigned short u = XBs[STO(n, tl)];
                st[n] = fmaxf((float)__builtin_bit_cast(_Float16, u) + bb, 0.0f);
            }
            float red[17];
#pragma unroll
            for (int p = 0; p < 17; ++p) {
                const int n = (p < 9) ? p : (p - 9);
                const int m = (p < 9) ? (p + 1) : (p - 9 + 2);
                red[p] = fast_tanh(st[n] - st[m]);
            }
#pragma unroll
            for (int stp = 1; stp < 64; stp <<= 1)
#pragma unroll
                for (int p = 0; p < 17; ++p) red[p] += __shfl_xor(red[p], stp);
            if (ln == 0) {
#pragma unroll
                for (int p = 0; p < 17; ++p) SMs[RED2 + wv * 17 + p] = red[p];
            }
        }
    }
    __syncthreads();

    // ---- P3: shot = relu(S0 . A_sta + b_info), BANDED A_sta computed
    // on the fly from RED2 (A_sta is band-2, antisymmetric, unit diag —
    // band_adj(10,2) masks everything else). No A_sta buffer, no P2b phase.
    {
        const int c0 = tl << 1;
        const float bi0 = b_info[c0], bi1 = b_info[c0 + 1];
#pragma unroll
        for (int sp = 0; sp < 2; ++sp) {
            unsigned short* SBs = SB + sp * SSTR;
            const float* SMs = SMf + sp * MSTR;
            float s1[9], s2[8];
#pragma unroll
            for (int k = 0; k < 9; ++k)
                s1[k] = (SMs[RED2 + k] + SMs[RED2 + 17 + k] +
                         SMs[RED2 + 34 + k] + SMs[RED2 + 51 + k]) * (1.0f / 256.0f);
#pragma unroll
            for (int k = 0; k < 8; ++k)
                s2[k] = (SMs[RED2 + 9 + k] + SMs[RED2 + 26 + k] +
                         SMs[RED2 + 43 + k] + SMs[RED2 + 60 + k]) * (1.0f / 256.0f);
            float sa[10], sb2[10];
#pragma unroll
            for (int n = 0; n < 10; ++n) {
                const h2 v = __builtin_bit_cast(h2, *(const unsigned int*)(SBs + SO(n, c0)));
                sa[n] = (float)v[0]; sb2[n] = (float)v[1];
            }
            unsigned int o10[10];
#pragma unroll
            for (int m = 0; m < 10; ++m) {
                float t0 = bi0 + sa[m], t1 = bi1 + sb2[m];
                if (m >= 1) { t0 += sa[m-1] * s1[m-1]; t1 += sb2[m-1] * s1[m-1]; }
                if (m <= 8) { t0 -= sa[m+1] * s1[m];   t1 -= sb2[m+1] * s1[m];   }
                if (m >= 2) { t0 += sa[m-2] * s2[m-2]; t1 += sb2[m-2] * s2[m-2]; }
                if (m <= 7) { t0 -= sa[m+2] * s2[m];   t1 -= sb2[m+2] * s2[m];   }
                o10[m] = __builtin_bit_cast(unsigned int, pk(fmaxf(t0, 0.0f), fmaxf(t1, 0.0f)));
            }
#pragma unroll
            for (int m = 0; m < 10; ++m)
                *(unsigned int*)(SBs + SO(m, c0)) = o10[m];
        }
    }
    __syncthreads();

    // ---- P4 (MFMA, 2 samples): q_d/k_d (K=512) + q_s/k_s (grouped K=64) ----
    {
        const f32x4 z = {0.0f, 0.0f, 0.0f, 0.0f};
        f32x4 qa[2][2], ka4[2][2];
#pragma unroll
        for (int sp = 0; sp < 2; ++sp)
#pragma unroll
            for (int h = 0; h < 2; ++h) { qa[sp][h] = z; ka4[sp][h] = z; }
        const unsigned short* wq0 = W16 + WQD + (((wv << 5) + ar) << 9);
        const unsigned short* wk0 = W16 + WKD + (((wv << 5) + ar) << 9);
        for (int kt = 0; kt < 16; ++kt) {
            const int ko = (kt << 5) + (kq << 3);
            const H8 bf0 = *(const H8*)(SB + SO(bn, ko));
            const H8 bf1 = *(const H8*)(SB + SSTR + SO(bn, ko));
            const H8 aq0 = *(const H8*)(wq0 + ko);
            const H8 aq1 = *(const H8*)(wq0 + (16 << 9) + ko);
            const H8 ak0 = *(const H8*)(wk0 + ko);
            const H8 ak1 = *(const H8*)(wk0 + (16 << 9) + ko);
            qa[0][0] = mfma16(aq0, bf0, qa[0][0]);
            qa[0][1] = mfma16(aq1, bf0, qa[0][1]);
            ka4[0][0] = mfma16(ak0, bf0, ka4[0][0]);
            ka4[0][1] = mfma16(ak1, bf0, ka4[0][1]);
            qa[1][0] = mfma16(aq0, bf1, qa[1][0]);
            qa[1][1] = mfma16(aq1, bf1, qa[1][1]);
            ka4[1][0] = mfma16(ak0, bf1, ka4[1][0]);
            ka4[1][1] = mfma16(ak1, bf1, ka4[1][1]);
        }
        if (ar < 10) {
            const int oc = (wv << 5) + (kq << 2);
#pragma unroll
            for (int sp = 0; sp < 2; ++sp) {
                unsigned short* XBs = XB + sp * XSTR;
                U2 u;
                u.x = __builtin_bit_cast(unsigned int, pk(qa[sp][0][0], qa[sp][0][1]));
                u.y = __builtin_bit_cast(unsigned int, pk(qa[sp][0][2], qa[sp][0][3]));
                *(U2*)(XBs + QDT + ar * 136 + oc) = u;
                u.x = __builtin_bit_cast(unsigned int, pk(qa[sp][1][0], qa[sp][1][1]));
                u.y = __builtin_bit_cast(unsigned int, pk(qa[sp][1][2], qa[sp][1][3]));
                *(U2*)(XBs + QDT + ar * 136 + oc + 16) = u;
                u.x = __builtin_bit_cast(unsigned int, pk(ka4[sp][0][0], ka4[sp][0][1]));
                u.y = __builtin_bit_cast(unsigned int, pk(ka4[sp][0][2], ka4[sp][0][3]));
                *(U2*)(XBs + KDT + ar * 136 + oc) = u;
                u.x = __builtin_bit_cast(unsigned int, pk(ka4[sp][1][0], ka4[sp][1][1]));
                u.y = __builtin_bit_cast(unsigned int, pk(ka4[sp][1][2], ka4[sp][1][3]));
                *(U2*)(XBs + KDT + ar * 136 + oc + 16) = u;
            }
        }
#pragma unroll
        for (int gi = 0; gi < 2; ++gi) {
            const int gs = (wv << 1) + gi;
            f32x4 qs[2], ks[2];
            qs[0] = z; qs[1] = z; ks[0] = z; ks[1] = z;
#pragma unroll
            for (int kt = 0; kt < 2; ++kt) {
                const int ko = (kt << 5) + (kq << 3);
                const H8 aq = *(const H8*)(W16 + WQS + (((gs << 4) + ar) << 6) + ko);
                const H8 ak = *(const H8*)(W16 + WKS + (((gs << 4) + ar) << 6) + ko);
                const H8 bf0 = *(const H8*)(SB + SO(bn, (gs << 6) + ko));
                const H8 bf1 = *(const H8*)(SB + SSTR + SO(bn, (gs << 6) + ko));
                qs[0] = mfma16(aq, bf0, qs[0]);
                ks[0] = mfma16(ak, bf0, ks[0]);
                qs[1] = mfma16(aq, bf1, qs[1]);
                ks[1] = mfma16(ak, bf1, ks[1]);
            }
            if (ar < 10) {
                const int oc = (gs << 4) + (kq << 2);
#pragma unroll
                for (int sp = 0; sp < 2; ++sp) {
                    unsigned short* XBs = XB + sp * XSTR;
                    U2 u;
                    u.x = __builtin_bit_cast(unsigned int, pk(qs[sp][0], qs[sp][1]));
                    u.y = __builtin_bit_cast(unsigned int, pk(qs[sp][2], qs[sp][3]));
                    *(U2*)(XBs + QST + ar * 136 + oc) = u;
                    u.x = __builtin_bit_cast(unsigned int, pk(ks[sp][0], ks[sp][1]));
                    u.y = __builtin_bit_cast(unsigned int, pk(ks[sp][2], ks[sp][3]));
                    *(U2*)(XBs + KST + ar * 136 + oc) = u;
                }
            }
        }
    }
    __syncthreads();

    // ---- P5: Bs|Bd logits, both samples ----
    if (tl < 200) {
        const int t = (tl < 100) ? tl : (tl - 100);
        const int n = t / 10, m = t - (t / 10) * 10;
        const int d = (n > m) ? (n - m) : (m - n);
        const float band = (d <= 3) ? 1.0f : 0.0f;
        const float Cv = (tl < 100) ? C_s[n * 10 + m] : C_d[n * 10 + m];
        const float al = (tl < 100) ? aS : aD;
        const int qoff = ((tl < 100) ? QST : QDT) + n * 136;
        const int koff = ((tl < 100) ? KST : KDT) + m * 136;
        const int dsto = (tl < 100) ? (BSO + t) : (BDO + t);
#pragma unroll
        for (int sp = 0; sp < 2; ++sp) {
            const unsigned short* q = XB + sp * XSTR + qoff;
            const unsigned short* k = XB + sp * XSTR + koff;
            float s = 0.0f;
#pragma unroll
            for (int c8 = 0; c8 < 16; ++c8) {
                const H8 qv = *(const H8*)(q + (c8 << 3));
                const H8 kv = *(const H8*)(k + (c8 << 3));
                s = dot4(qv, kv, s);
            }
            SMf[sp * MSTR + dsto] = al * (s * RSQRT128) + Cv + band;
        }
    }
    __syncthreads();

    // ---- P6: Y0 + PRD partials + softmaxes, both samples ----
    {
        const int p = tl >> 1, kh = tl & 1;
        const int gs = p >> 4, ls = p & 15;
        const int o0 = (gs << 5) + ls, o1 = o0 + 16;
        const int cb = (gs << 6) + (kh << 5);
        const unsigned short* w0 = W16 + WSA + (o0 << 6) + (kh << 5);
        const unsigned short* w1 = W16 + WSA + (o1 << 6) + (kh << 5);
#pragma unroll
        for (int sp = 0; sp < 2; ++sp) {
            const unsigned short* SBs = SB + sp * SSTR;
            float a0[10], a1[10];
#pragma unroll
            for (int n = 0; n < 10; ++n) { a0[n] = 0.0f; a1[n] = 0.0f; }
#pragma unroll
            for (int c8 = 0; c8 < 4; ++c8) {
                const H8 wv0 = *(const H8*)(w0 + (c8 << 3));
                const H8 wv1 = *(const H8*)(w1 + (c8 << 3));
#pragma unroll
                for (int n = 0; n < 10; ++n) {
                    const H8 sv = *(const H8*)(SBs + SO(n, cb + (c8 << 3)));
                    a0[n] = dot4(sv, wv0, a0[n]);
                    a1[n] = dot4(sv, wv1, a1[n]);
                }
            }
#pragma unroll
            for (int n = 0; n < 10; ++n) {
                a0[n] += __shfl_xor(a0[n], 1);
                a1[n] += __shfl_xor(a1[n], 1);
            }
            float* yr = (float*)(XB + sp * XSTR) + (kh ? o1 : o0) * 11;
            const float* src = kh ? a1 : a0;
#pragma unroll
            for (int n = 0; n < 10; ++n) yr[n] = src[n];
        }
    }
    for (int tt = tl; tt < 560; tt += 256) {
        const int sp = (tt >= 280) ? 1 : 0;
        const int t2 = tt - sp * 280;
        const int o = t2 / 40;
        const int rem = t2 - o * 40;
        const int n = rem >> 2, part = rem & 3;
        const unsigned short* wr = W16 + WDA + (o << 9) + (part << 7);
        const unsigned short* SBs = SB + sp * SSTR;
        float s = 0.0f;
#pragma unroll
        for (int j8 = 0; j8 < 16; ++j8) {
            const H8 wv2 = *(const H8*)(wr + (j8 << 3));
            const H8 sv = *(const H8*)(SBs + SO(n, (part << 7) + (j8 << 3)));
            s = dot4(sv, wv2, s);
        }
        SMf[sp * MSTR + PRD + t2] = s;
    }
    if (tl >= 216) {
        const int idx = tl - 216;           // 0..39 = 2 samples x 20 rows
        const int sp = idx / 20;
        const int r = idx - sp * 20;
        float* base = SMf + sp * MSTR + ((r < 10) ? (BSO + r * 10) : (BDO + (r - 10) * 10));
        softmax10(base);
    }
    __syncthreads();

    // ---- P7 (merged): ys = relu(Y0 . As + b_sagg) in place (all threads),
    // and T = S_d + aDf*relu(P0 . Ad + b_dagg) with P0 summed directly from
    // PRD (no P0 buffer, no extra barrier).
    {
        const float bs = b_sagg[tl];
#pragma unroll
        for (int sp = 0; sp < 2; ++sp) {
            float* yr = (float*)(XB + sp * XSTR) + tl * 11;
            const float* SMs = SMf + sp * MSTR;
            float r[10];
#pragma unroll
            for (int n = 0; n < 10; ++n) r[n] = yr[n];
            float ys[10];
#pragma unroll
            for (int m = 0; m < 10; ++m) {
                float a = bs;
#pragma unroll
                for (int n = 0; n < 10; ++n) a += r[n] * SMs[BSO + n * 10 + m];
                ys[m] = fmaxf(a, 0.0f);
            }
#pragma unroll
            for (int m = 0; m < 10; ++m) yr[m] = ys[m];
        }
    }
    if (tl < 140) {
        const int sp = tl / 70;
        const int t2 = tl - sp * 70;
        const int o = t2 / 10, m = t2 - (t2 / 10) * 10;
        float* SMs = SMf + sp * MSTR;
        float a = b_dagg[o];
#pragma unroll
        for (int n = 0; n < 10; ++n) {
            const float* pr = SMs + PRD + o * 40 + (n << 2);
            const float p0 = pr[0] + pr[1] + pr[2] + pr[3];
            a += p0 * SMs[BDO + n * 10 + m];
        }
        SMs[TTO + t2] = S_d[o * 10 + m] + aDf * fmaxf(a, 0.0f);
    }
    __syncthreads();

    // ---- P8: sceneT[m][c] = sum_n ys[c][n] * T[m][n], per sample -> SB f32 ----
#pragma unroll
    for (int sp = 0; sp < 2; ++sp) {
        const float* yr = (float*)(XB + sp * XSTR) + tl * 11;
        const float* SMs = SMf + sp * MSTR;
        float* SCFs = (float*)(SB + sp * SSTR);
        float r[10];
#pragma unroll
        for (int n = 0; n < 10; ++n) r[n] = yr[n];
#pragma unroll
        for (int m = 0; m < 7; ++m) {
            float a = 0.0f;
#pragma unroll
            for (int n = 0; n < 10; ++n) a += r[n] * SMs[TTO + m * 10 + n];
            SCFs[m * SCT + tl] = a;      // transposed: row m contiguous over c
        }
    }
    __syncthreads();

    // ---- P9+P10: v = relu(gconv(scene, w_mot)) + head partials, per sample ----
    if (tl < 128) {
        const int o = tl;
        const int cb = (o >> 4) << 5;
        float wr[32];
#pragma unroll
        for (int i4 = 0; i4 < 8; ++i4) {
            const float4 w4 = *(const float4*)(w_mot + (o << 5) + (i4 << 2));
            wr[i4 * 4 + 0] = w4.x; wr[i4 * 4 + 1] = w4.y;
            wr[i4 * 4 + 2] = w4.z; wr[i4 * 4 + 3] = w4.w;
        }
        const float bm = b_mot[o];
        const float wm = w_mean[o], wl = w_logv[o];
#pragma unroll
        for (int sp = 0; sp < 2; ++sp) {
            const float* SCFs = (float*)(SB + sp * SSTR);
            float mu_p[7], lv_p[7];
#pragma unroll
            for (int s = 0; s < 7; ++s) {
                float a = bm;
                const float4* rp = (const float4*)(SCFs + s * SCT + cb);
#pragma unroll
                for (int i = 0; i < 8; ++i) {
                    const float4 v4 = rp[i];
                    a += wr[4 * i] * v4.x + wr[4 * i + 1] * v4.y +
                         wr[4 * i + 2] * v4.z + wr[4 * i + 3] * v4.w;
                }
                const float v = fmaxf(a, 0.0f);
                mu_p[s] = v * wm; lv_p[s] = v * wl;
            }
#pragma unroll
            for (int stp = 1; stp < 64; stp <<= 1)
#pragma unroll
                for (int s = 0; s < 7; ++s) {
                    mu_p[s] += __shfl_xor(mu_p[s], stp);
                    lv_p[s] += __shfl_xor(lv_p[s], stp);
                }
            if ((tl & 63) == 0) {
                const int w = tl >> 6;
                float* SMs = SMf + sp * MSTR;
#pragma unroll
                for (int s = 0; s < 7; ++s) {
                    SMs[MUO + w * 14 + s]     = mu_p[s];
                    SMs[MUO + w * 14 + 7 + s] = lv_p[s];
                }
            }
        }
    }
    __syncthreads();

    // ---- P11: reparameterize + writes, both samples ----
    if (tl < 64) {
#pragma unroll
        for (int sp = 0; sp < 2; ++sp) {
            const float* SMs = SMf + sp * MSTR;
            const long bb2 = sp ? b1 : b0;
            float sc = 0.0f;
            if (tl < 7) {
                const float mu = b_mean[0] + SMs[MUO + tl] + SMs[MUO + 14 + tl];
                const float lv = b_logv[0] + SMs[MUO + 7 + tl] + SMs[MUO + 21 + tl];
                const float sd = __expf(0.5f * lv);
                sc = mu + sd * esp[bb2 * 7 + tl];
                out[(long)B + bb2 * 7 + tl]     = mu;
                out[(long)B * 8 + bb2 * 7 + tl] = sd;
            }
#pragma unroll
            for (int stp = 1; stp < 8; stp <<= 1) sc += __shfl_xor(sc, stp);
            if (tl == 0) out[bb2] = sc;
        }
    }
}

extern "C" void kernel_launch(void* const* d_in, const int* in_sizes, int n_in,
                              void* d_out, int out_size, void* d_ws, size_t ws_size,
                              hipStream_t stream) {
    (void)n_in; (void)out_size; (void)d_ws; (void)ws_size;
    const int B = in_sizes[0] / 10240;
    if (B <= 0) return;

    cvt_w<<<dim3((WTOT / 2 + 255) / 256), dim3(256), 0, stream>>>(
        (const float*)d_in[2],  (const float*)d_in[4],  (const float*)d_in[6],
        (const float*)d_in[7],  (const float*)d_in[10], (const float*)d_in[12],
        (const float*)d_in[13], (const float*)d_in[16]);

    hgcn_fused<<<dim3((B + 1) / 2), dim3(256), 0, stream>>>(
        (const float*)d_in[0],  (const float*)d_in[1],  (const float*)d_in[3],
        (const float*)d_in[5],  (const float*)d_in[8],  (const float*)d_in[9],
        (const float*)d_in[11], (const float*)d_in[14], (const float*)d_in[15],
        (const float*)d_in[17], (const float*)d_in[18], (const float*)d_in[19],
        (const float*)d_in[20], (const float*)d_in[21], (const float*)d_in[22],
        (const float*)d_in[23], (const float*)d_in[24], (const float*)d_in[25],
        (float*)d_out, B);
}